// Round 22
// baseline (132.900 us; speedup 1.0000x reference)
//
#include <hip/hip_runtime.h>

typedef __fp16 f16;
typedef __fp16 f16x2 __attribute__((ext_vector_type(2)));
typedef __fp16 f16x8 __attribute__((ext_vector_type(8)));
typedef float f32x4 __attribute__((ext_vector_type(4)));
typedef float f32x16 __attribute__((ext_vector_type(16)));

__device__ __forceinline__ unsigned pkrtz(float a, float b) {
    f16x2 r = __builtin_amdgcn_cvt_pkrtz(a, b);
    return __builtin_bit_cast(unsigned, r);
}

__device__ __forceinline__ f16x8 pack4(unsigned a, unsigned b, unsigned c, unsigned d) {
    union { unsigned u[4]; f16x8 v; } r;
    r.u[0] = a; r.u[1] = b; r.u[2] = c; r.u[3] = d;
    return r.v;
}

// Async global->LDS DMA, 16B per lane. LDS dest = uniform base + lane*16.
__device__ __forceinline__ void glds16(const void* g, void* l) {
    __builtin_amdgcn_global_load_lds(
        (const __attribute__((address_space(1))) unsigned*)g,
        (__attribute__((address_space(3))) unsigned*)l, 16, 0, 0);
}

// Pack 30 weight matrices (64x64, row=k input, col=m output) into f16
// A-fragment order for v_mfma_f32_32x32x16_f16:
//   lane l holds A[m = l&31][k = 16*kt + 4*(l>>5) + (e&3) + 8*(e>=4)], mtile adds 32 to m.
__global__ __launch_bounds__(512) void pack_w(
    const float* __restrict__ sW1, const float* __restrict__ sW2, const float* __restrict__ sW3,
    const float* __restrict__ tW1, const float* __restrict__ tW2, const float* __restrict__ tW3,
    f16* __restrict__ wp) {
    int mat = blockIdx.x;            // layer*6 + {sW1,sW2,sW3,tW1,tW2,tW3}
    int layer = mat / 6;
    int rem = mat % 6;
    int fi = threadIdx.x >> 6;       // 0..7
    int lane = threadIdx.x & 63;
    int tile = fi >> 2, kt = fi & 3;
    int h = lane >> 5;
    int m = (lane & 31) + 32 * tile;
    const float* Wt[6] = {sW1, sW2, sW3, tW1, tW2, tW3};
    const float* W = Wt[rem] + layer * 4096;
    f16x8 v;
#pragma unroll
    for (int e = 0; e < 8; ++e) {
        int k = 16 * kt + 4 * h + (e & 3) + ((e >> 2) << 3);
        v[e] = (f16)W[k * 64 + m];
    }
    *(f16x8*)(wp + ((size_t)mat * 8 + fi) * 512 + lane * 8) = v;
}

// Per path-block pb = l*2+p (512 B at wb + pb*512):
//   [0,128)   g1 bias as f16, order o = h*32 + kt*8 + e
//   [128,256) g2 bias as f16, same order
//   [256,512) g3 bias as f32, plain m order
__global__ __launch_bounds__(512) void pack_b(
    const float* __restrict__ sb1, const float* __restrict__ sb2, const float* __restrict__ sb3,
    const float* __restrict__ tb1, const float* __restrict__ tb2, const float* __restrict__ tb3,
    char* __restrict__ wb) {
    int i = blockIdx.x * 512 + threadIdx.x;   // 10 path-blocks x 192 entries
    if (i >= 1920) return;
    int pb = i / 192, o = i % 192;
    int l = pb >> 1, p = pb & 1;
    char* base = wb + (size_t)pb * 512;
    if (o < 128) {
        int g = o >> 6, oo = o & 63;
        int h = oo >> 5, kt = (oo >> 3) & 3, e = oo & 7;
        int m = 32 * (kt >> 1) + 16 * (kt & 1) + 8 * (e >> 2) + 4 * h + (e & 3);
        const float* B = g == 0 ? (p ? tb1 : sb1) : (p ? tb2 : sb2);
        ((f16*)base)[g * 64 + oo] = (f16)B[l * 64 + m];
    } else {
        int oo = o - 128;
        const float* B = p ? tb3 : sb3;
        ((float*)(base + 256))[oo] = B[l * 64 + oo];
    }
}

// f32 bias (LDS broadcast) accumulator init — used for GEMM3 only.
__device__ __forceinline__ void bias_init(const float* bias, int h, f32x16 c[2]) {
#pragma unroll
    for (int t = 0; t < 2; ++t) {
#pragma unroll
        for (int r4 = 0; r4 < 4; ++r4) {
            f32x4 bb = *(const f32x4*)(bias + 32 * t + 8 * r4 + 4 * h);
            c[t][4 * r4 + 0] = bb[0];
            c[t][4 * r4 + 1] = bb[1];
            c[t][4 * r4 + 2] = bb[2];
            c[t][4 * r4 + 3] = bb[3];
        }
    }
}

// Zero-init 64x64 GEMM (bias applied later in f16): 8 ds_read_b128, 8 MFMA.
__device__ __forceinline__ void gemm_z(const f16* w, const f16x8 in[4],
                                       int lane, f32x16 c[2]) {
#pragma unroll
    for (int mt = 0; mt < 2; ++mt)
#pragma unroll
        for (int j = 0; j < 16; ++j) c[mt][j] = 0.f;
    __builtin_amdgcn_s_setprio(1);
#pragma unroll
    for (int mt = 0; mt < 2; ++mt) {
#pragma unroll
        for (int kt = 0; kt < 4; ++kt) {
            f16x8 wf = *(const f16x8*)(w + (mt * 4 + kt) * 512 + lane * 8);
            c[mt] = __builtin_amdgcn_mfma_f32_32x32x16_f16(wf, in[kt], c[mt], 0, 0, 0);
        }
    }
    __builtin_amdgcn_s_setprio(0);
}

// Bias-init 64x64 GEMM (f32 bias from LDS) — GEMM3.
__device__ __forceinline__ void gemm_b(const f16* w, const f16x8 in[4],
                                       const float* bias, int lane, f32x16 c[2]) {
    const int h = (lane >> 5) & 1;
    bias_init(bias, h, c);
    __builtin_amdgcn_s_setprio(1);
#pragma unroll
    for (int mt = 0; mt < 2; ++mt) {
#pragma unroll
        for (int kt = 0; kt < 4; ++kt) {
            f16x8 wf = *(const f16x8*)(w + (mt * 4 + kt) * 512 + lane * 8);
            c[mt] = __builtin_amdgcn_mfma_f32_32x32x16_f16(wf, in[kt], c[mt], 0, 0, 0);
        }
    }
    __builtin_amdgcn_s_setprio(0);
}

// bias-add (f16 packed, 1 ds_read_b128 per kt) + leaky_relu + B-frag pack.
// bb points at this gemm's f16 bias block, pre-offset by h*32 elements.
// B-frag[kt][e] = C[mt = kt>>1][reg = 8*(kt&1) + e]  (register-local)
__device__ __forceinline__ void relu_pack_b(const f32x16 c[2], const f16* bb, f16x8 o[4]) {
    const f16 hc = (f16)0.01f;
    const f16x8 c001 = {hc, hc, hc, hc, hc, hc, hc, hc};
#pragma unroll
    for (int kt = 0; kt < 4; ++kt) {
        const int tl = kt >> 1;
        const int base = 8 * (kt & 1);
        f16x8 b = *(const f16x8*)(bb + kt * 8);
        f16x8 v = pack4(pkrtz(c[tl][base + 0], c[tl][base + 1]),
                        pkrtz(c[tl][base + 2], c[tl][base + 3]),
                        pkrtz(c[tl][base + 4], c[tl][base + 5]),
                        pkrtz(c[tl][base + 6], c[tl][base + 7])) + b;
        o[kt] = __builtin_elementwise_max(v, v * c001);   // v_pk_max / v_pk_mul
    }
}

// 3-GEMM MLP (one path) from one LDS slot.
// Slot layout: [0,24576) weights; [24576,24832) f16 biases g1,g2; [24832,25088) f32 bias g3.
__device__ __forceinline__ void mlp3(const char* slot, const f16x8 x0f[4],
                                     int lane, f32x16 out[2]) {
    const f16* w = (const f16*)slot;
    const int h = (lane >> 5) & 1;
    const f16* b16 = (const f16*)(slot + 24576) + h * 32;
    const float* b3 = (const float*)(slot + 24832);
    f32x16 c1[2];
    gemm_z(w, x0f, lane, c1);
    f16x8 h1[4];
    relu_pack_b(c1, b16, h1);
    f32x16 c2[2];
    gemm_z(w + 4096, h1, lane, c2);
    f16x8 h2[4];
    relu_pack_b(c2, b16 + 64, h2);
    gemm_b(w + 8192, h2, b3, lane, out);
}

#define SLOTB 25088

__global__ __launch_bounds__(512, 2)
void flow_main(const float* __restrict__ x, const f16* __restrict__ wp,
               float* __restrict__ out, int nrows) {
    __shared__ char wl[2 * SLOTB];   // slot0 = s-path, slot1 = t-path (alternating DMA)
    const int tid = threadIdx.x;
    const int lane = tid & 63;
    const int wv = tid >> 6;                                    // 0..7
    const int h = lane >> 5;
    const int n = (blockIdx.x * 8 + wv) * 32 + (lane & 31);     // 32 rows per wave
    const float* xr = x + (size_t)n * 128;
    float* zr = out + (size_t)n * 128;
    const char* wp_b = (const char*)wp;            // path pi: weights at pi*24576
    const char* wb_b = (const char*)wp + 491520;   // path pi: biases at pi*512

    // Issue DMA: path pi -> slot (weights 24576B as 24 chunks x 1024B; biases 512B).
    auto stage = [&](int pi, char* slot) {
#pragma unroll
        for (int j = 0; j < 3; ++j) {
            const int chunk = wv + j * 8;
            glds16(wp_b + (size_t)pi * 24576 + chunk * 1024 + lane * 16,
                   slot + chunk * 1024);
        }
        if (wv == 0 && lane < 32)
            glds16(wb_b + (size_t)pi * 512 + lane * 16, slot + 24576);
    };

    // Prologue: DMA s0 -> slot0.
    stage(0, wl);

    // Load x0 (B-fragment gather), copy to z[:, :64], convert to f16 frags.
    f16x8 x0f[4];
#pragma unroll
    for (int kt = 0; kt < 4; ++kt) {
        f32x4 a = *(const f32x4*)(xr + 16 * kt + 4 * h);
        f32x4 b = *(const f32x4*)(xr + 16 * kt + 8 + 4 * h);
        *(f32x4*)(zr + 16 * kt + 4 * h) = a;
        *(f32x4*)(zr + 16 * kt + 8 + 4 * h) = b;
        x0f[kt] = pack4(pkrtz(a[0], a[1]), pkrtz(a[2], a[3]), pkrtz(b[0], b[1]), pkrtz(b[2], b[3]));
    }

    // x1 resident as packed f16 (16 regs). x1h[t*2+q][e] <-> feature 32t+16q+8*(e>=4)+4h+(e&3)
    f16x8 x1h[4];
#pragma unroll
    for (int i = 0; i < 4; ++i) {
        const int t = i >> 1, q = i & 1;
        f32x4 a = *(const f32x4*)(xr + 64 + 32 * t + 16 * q + 4 * h);
        f32x4 b = *(const f32x4*)(xr + 64 + 32 * t + 16 * q + 8 + 4 * h);
        x1h[i] = pack4(pkrtz(a[0], a[1]), pkrtz(a[2], a[3]),
                       pkrtz(b[0], b[1]), pkrtz(b[2], b[3]));
    }

    __syncthreads();   // implicit vmcnt(0) drain: s0 DMA complete

    // logdet via Σs = count - 2·Σrc  (rc = 1/(e^{2y}+1); s = tanh(y) = 1-2rc)
    float sumrc = 0.f;

    // One half of the s-epilogue: cs[t] elements 8q..8q+7 -> x1h[2t+q] *= exp(tanh(y)).
    auto epi_half = [&](const f32x16* cs, int i) {
        const int t = i >> 1, q = i & 1;
        float ef[8];
#pragma unroll
        for (int e = 0; e < 8; ++e) {
            float y = cs[t][8 * q + e];
            float u = __builtin_amdgcn_exp2f(2.8853900817779268f * y);  // e^{2y}
            float rc = __builtin_amdgcn_rcpf(u + 1.f);
            sumrc += rc;
            ef[e] = __builtin_amdgcn_exp2f(fmaf(-2.8853900817779268f, rc, 1.4426950408889634f)); // e^{tanh}
        }
        f16x8 efp = pack4(pkrtz(ef[0], ef[1]), pkrtz(ef[2], ef[3]),
                          pkrtz(ef[4], ef[5]), pkrtz(ef[6], ef[7]));
        x1h[i] = x1h[i] * efp;   // v_pk_mul_f16
    };

#pragma unroll 1
    for (int l = 0; l < 5; ++l) {
        // ---- s phase: compute from slot0; DMA t_l -> slot1 flies under it ----
        stage(2 * l + 1, wl + SLOTB);

        f32x16 cs[2];
        mlp3(wl, x0f, lane, cs);

        __syncthreads();   // slot0 reads done; slot1 DMA drained

        // ---- t phase, interleaved with the s-epilogue (trans hides under MFMA) ----
        if (l < 4) stage(2 * l + 2, wl);   // DMA s_{l+1} -> slot0

        const char* slot1 = wl + SLOTB;
        const f16* wT = (const f16*)slot1;
        const f16* b16 = (const f16*)(slot1 + 24576) + h * 32;
        const float* b3 = (const float*)(slot1 + 24832);

        f32x16 c1[2];
        gemm_z(wT, x0f, lane, c1);
        epi_half(cs, 0);                   // cs[0] low half
        epi_half(cs, 1);                   // cs[0] high half
        f16x8 h1[4];
        relu_pack_b(c1, b16, h1);
        f32x16 c2[2];
        gemm_z(wT + 4096, h1, lane, c2);
        epi_half(cs, 2);                   // cs[1] low half
        epi_half(cs, 3);                   // cs[1] high half  (cs fully dead)
        f16x8 h2[4];
        relu_pack_b(c2, b16 + 64, h2);
        f32x16 ct[2];
        gemm_b(wT + 8192, h2, b3, lane, ct);

        // x1 += t, packed f16
#pragma unroll
        for (int i = 0; i < 4; ++i) {
            const int t = i >> 1, q = i & 1;
            f16x8 tp = pack4(pkrtz(ct[t][8 * q + 0], ct[t][8 * q + 1]),
                             pkrtz(ct[t][8 * q + 2], ct[t][8 * q + 3]),
                             pkrtz(ct[t][8 * q + 4], ct[t][8 * q + 5]),
                             pkrtz(ct[t][8 * q + 6], ct[t][8 * q + 7]));
            x1h[i] = x1h[i] + tp;   // v_pk_add_f16
        }

        __syncthreads();   // slot1 reads done; slot0 DMA drained
    }

    // Store z[:, 64:]
#pragma unroll
    for (int i = 0; i < 4; ++i) {
        const int t = i >> 1, q = i & 1;
        f16x8 v = x1h[i];
        f32x4 a = {(float)v[0], (float)v[1], (float)v[2], (float)v[3]};
        f32x4 b = {(float)v[4], (float)v[5], (float)v[6], (float)v[7]};
        *(f32x4*)(zr + 64 + 32 * t + 16 * q + 4 * h) = a;
        *(f32x4*)(zr + 64 + 32 * t + 16 * q + 8 + 4 * h) = b;
    }

    // log_det = 320 - 2·Σrc (both lane halves); lane n and n+32 split the features.
    float sr2 = sumrc + __shfl_xor(sumrc, 32);
    if (h == 0) out[(size_t)nrows * 128 + n] = fmaf(-2.f, sr2, 320.f);
}

extern "C" void kernel_launch(void* const* d_in, const int* in_sizes, int n_in,
                              void* d_out, int out_size, void* d_ws, size_t ws_size,
                              hipStream_t stream) {
    const float* x   = (const float*)d_in[0];
    const float* sW1 = (const float*)d_in[1];
    const float* sb1 = (const float*)d_in[2];
    const float* sW2 = (const float*)d_in[3];
    const float* sb2 = (const float*)d_in[4];
    const float* sW3 = (const float*)d_in[5];
    const float* sb3 = (const float*)d_in[6];
    const float* tW1 = (const float*)d_in[7];
    const float* tb1 = (const float*)d_in[8];
    const float* tW2 = (const float*)d_in[9];
    const float* tb2 = (const float*)d_in[10];
    const float* tW3 = (const float*)d_in[11];
    const float* tb3 = (const float*)d_in[12];

    f16* wp = (f16*)d_ws;      // weights: 240 KB frag-packed (path-major); biases at +480 KB
    char* wb = (char*)d_ws + 491520;
    int nrows = in_sizes[0] / 128;

    pack_w<<<30, 512, 0, stream>>>(sW1, sW2, sW3, tW1, tW2, tW3, wp);
    pack_b<<<4, 512, 0, stream>>>(sb1, sb2, sb3, tb1, tb2, tb3, wb);
    flow_main<<<nrows / 256, 512, 0, stream>>>(x, wp, (float*)d_out, nrows);
}

// Round 23
// 112.925 us; speedup vs baseline: 1.1769x; 1.1769x over previous
//
#include <hip/hip_runtime.h>

typedef __fp16 f16;
typedef __fp16 f16x2 __attribute__((ext_vector_type(2)));
typedef __fp16 f16x8 __attribute__((ext_vector_type(8)));
typedef float f32x4 __attribute__((ext_vector_type(4)));
typedef float f32x16 __attribute__((ext_vector_type(16)));

__device__ __forceinline__ unsigned pkrtz(float a, float b) {
    f16x2 r = __builtin_amdgcn_cvt_pkrtz(a, b);
    return __builtin_bit_cast(unsigned, r);
}

__device__ __forceinline__ f16x8 pack4(unsigned a, unsigned b, unsigned c, unsigned d) {
    union { unsigned u[4]; f16x8 v; } r;
    r.u[0] = a; r.u[1] = b; r.u[2] = c; r.u[3] = d;
    return r.v;
}

// Async global->LDS DMA, 16B per lane. LDS dest = uniform base + lane*16.
__device__ __forceinline__ void glds16(const void* g, void* l) {
    __builtin_amdgcn_global_load_lds(
        (const __attribute__((address_space(1))) unsigned*)g,
        (__attribute__((address_space(3))) unsigned*)l, 16, 0, 0);
}

// Pack 30 weight matrices (64x64, row=k input, col=m output) into f16
// A-fragment order for v_mfma_f32_32x32x16_f16:
//   lane l holds A[m = l&31][k = 16*kt + 4*(l>>5) + (e&3) + 8*(e>=4)], mtile adds 32 to m.
__global__ __launch_bounds__(512) void pack_w(
    const float* __restrict__ sW1, const float* __restrict__ sW2, const float* __restrict__ sW3,
    const float* __restrict__ tW1, const float* __restrict__ tW2, const float* __restrict__ tW3,
    f16* __restrict__ wp) {
    int mat = blockIdx.x;            // layer*6 + {sW1,sW2,sW3,tW1,tW2,tW3}
    int layer = mat / 6;
    int rem = mat % 6;
    int fi = threadIdx.x >> 6;       // 0..7
    int lane = threadIdx.x & 63;
    int tile = fi >> 2, kt = fi & 3;
    int h = lane >> 5;
    int m = (lane & 31) + 32 * tile;
    const float* Wt[6] = {sW1, sW2, sW3, tW1, tW2, tW3};
    const float* W = Wt[rem] + layer * 4096;
    f16x8 v;
#pragma unroll
    for (int e = 0; e < 8; ++e) {
        int k = 16 * kt + 4 * h + (e & 3) + ((e >> 2) << 3);
        v[e] = (f16)W[k * 64 + m];
    }
    *(f16x8*)(wp + ((size_t)mat * 8 + fi) * 512 + lane * 8) = v;
}

// Per path-block pb = l*2+p (512 B at wb + pb*512):
//   [0,128)   g1 bias as f16, order o = h*32 + kt*8 + e
//   [128,256) g2 bias as f16, same order
//   [256,512) g3 bias as f32, plain m order
__global__ __launch_bounds__(512) void pack_b(
    const float* __restrict__ sb1, const float* __restrict__ sb2, const float* __restrict__ sb3,
    const float* __restrict__ tb1, const float* __restrict__ tb2, const float* __restrict__ tb3,
    char* __restrict__ wb) {
    int i = blockIdx.x * 512 + threadIdx.x;   // 10 path-blocks x 192 entries
    if (i >= 1920) return;
    int pb = i / 192, o = i % 192;
    int l = pb >> 1, p = pb & 1;
    char* base = wb + (size_t)pb * 512;
    if (o < 128) {
        int g = o >> 6, oo = o & 63;
        int h = oo >> 5, kt = (oo >> 3) & 3, e = oo & 7;
        int m = 32 * (kt >> 1) + 16 * (kt & 1) + 8 * (e >> 2) + 4 * h + (e & 3);
        const float* B = g == 0 ? (p ? tb1 : sb1) : (p ? tb2 : sb2);
        ((f16*)base)[g * 64 + oo] = (f16)B[l * 64 + m];
    } else {
        int oo = o - 128;
        const float* B = p ? tb3 : sb3;
        ((float*)(base + 256))[oo] = B[l * 64 + oo];
    }
}

// f32 bias (LDS broadcast) accumulator init — used for GEMM3 only.
__device__ __forceinline__ void bias_init(const float* bias, int h, f32x16 c[2]) {
#pragma unroll
    for (int t = 0; t < 2; ++t) {
#pragma unroll
        for (int r4 = 0; r4 < 4; ++r4) {
            f32x4 bb = *(const f32x4*)(bias + 32 * t + 8 * r4 + 4 * h);
            c[t][4 * r4 + 0] = bb[0];
            c[t][4 * r4 + 1] = bb[1];
            c[t][4 * r4 + 2] = bb[2];
            c[t][4 * r4 + 3] = bb[3];
        }
    }
}

// Zero-init 64x64 GEMM (bias applied later in f16): 8 ds_read_b128, 8 MFMA.
__device__ __forceinline__ void gemm_z(const f16* w, const f16x8 in[4],
                                       int lane, f32x16 c[2]) {
#pragma unroll
    for (int mt = 0; mt < 2; ++mt)
#pragma unroll
        for (int j = 0; j < 16; ++j) c[mt][j] = 0.f;
#pragma unroll
    for (int mt = 0; mt < 2; ++mt) {
#pragma unroll
        for (int kt = 0; kt < 4; ++kt) {
            f16x8 wf = *(const f16x8*)(w + (mt * 4 + kt) * 512 + lane * 8);
            c[mt] = __builtin_amdgcn_mfma_f32_32x32x16_f16(wf, in[kt], c[mt], 0, 0, 0);
        }
    }
}

// Bias-init 64x64 GEMM (f32 bias from LDS) — GEMM3.
__device__ __forceinline__ void gemm_b(const f16* w, const f16x8 in[4],
                                       const float* bias, int lane, f32x16 c[2]) {
    const int h = (lane >> 5) & 1;
    bias_init(bias, h, c);
#pragma unroll
    for (int mt = 0; mt < 2; ++mt) {
#pragma unroll
        for (int kt = 0; kt < 4; ++kt) {
            f16x8 wf = *(const f16x8*)(w + (mt * 4 + kt) * 512 + lane * 8);
            c[mt] = __builtin_amdgcn_mfma_f32_32x32x16_f16(wf, in[kt], c[mt], 0, 0, 0);
        }
    }
}

// bias-add (f16 packed, 1 ds_read_b128 per kt) + leaky_relu + B-frag pack.
// bb points at this gemm's f16 bias block, pre-offset by h*32 elements.
// B-frag[kt][e] = C[mt = kt>>1][reg = 8*(kt&1) + e]  (register-local)
__device__ __forceinline__ void relu_pack_b(const f32x16 c[2], const f16* bb, f16x8 o[4]) {
    const f16 hc = (f16)0.01f;
    const f16x8 c001 = {hc, hc, hc, hc, hc, hc, hc, hc};
#pragma unroll
    for (int kt = 0; kt < 4; ++kt) {
        const int tl = kt >> 1;
        const int base = 8 * (kt & 1);
        f16x8 b = *(const f16x8*)(bb + kt * 8);
        f16x8 v = pack4(pkrtz(c[tl][base + 0], c[tl][base + 1]),
                        pkrtz(c[tl][base + 2], c[tl][base + 3]),
                        pkrtz(c[tl][base + 4], c[tl][base + 5]),
                        pkrtz(c[tl][base + 6], c[tl][base + 7])) + b;
        o[kt] = __builtin_elementwise_max(v, v * c001);   // v_pk_max / v_pk_mul
    }
}

// 3-GEMM MLP (one path) from one LDS slot.
// Slot layout: [0,24576) weights; [24576,24832) f16 biases g1,g2; [24832,25088) f32 bias g3.
__device__ __forceinline__ void mlp3(const char* slot, const f16x8 x0f[4],
                                     int lane, f32x16 out[2]) {
    const f16* w = (const f16*)slot;
    const int h = (lane >> 5) & 1;
    const f16* b16 = (const f16*)(slot + 24576) + h * 32;
    const float* b3 = (const float*)(slot + 24832);
    f32x16 c1[2];
    gemm_z(w, x0f, lane, c1);
    f16x8 h1[4];
    relu_pack_b(c1, b16, h1);
    f32x16 c2[2];
    gemm_z(w + 4096, h1, lane, c2);
    f16x8 h2[4];
    relu_pack_b(c2, b16 + 64, h2);
    gemm_b(w + 8192, h2, b3, lane, out);
}

#define SLOTB 25088

__global__ __launch_bounds__(512, 2)
void flow_main(const float* __restrict__ x, const f16* __restrict__ wp,
               float* __restrict__ out, int nrows) {
    __shared__ char wl[2 * SLOTB];   // slot0 = s-path, slot1 = t-path (alternating DMA)
    const int tid = threadIdx.x;
    const int lane = tid & 63;
    const int wv = tid >> 6;                                    // 0..7
    const int h = lane >> 5;
    const int n = (blockIdx.x * 8 + wv) * 32 + (lane & 31);     // 32 rows per wave
    const float* xr = x + (size_t)n * 128;
    float* zr = out + (size_t)n * 128;
    const char* wp_b = (const char*)wp;            // path pi: weights at pi*24576
    const char* wb_b = (const char*)wp + 491520;   // path pi: biases at pi*512

    // Issue DMA: path pi -> slot (weights 24576B as 24 chunks x 1024B; biases 512B).
    auto stage = [&](int pi, char* slot) {
#pragma unroll
        for (int j = 0; j < 3; ++j) {
            const int chunk = wv + j * 8;
            glds16(wp_b + (size_t)pi * 24576 + chunk * 1024 + lane * 16,
                   slot + chunk * 1024);
        }
        if (wv == 0 && lane < 32)
            glds16(wb_b + (size_t)pi * 512 + lane * 16, slot + 24576);
    };

    // Prologue: DMA s0 -> slot0.
    stage(0, wl);

    // Load x0 (B-fragment gather), copy to z[:, :64], convert to f16 frags.
    f16x8 x0f[4];
#pragma unroll
    for (int kt = 0; kt < 4; ++kt) {
        f32x4 a = *(const f32x4*)(xr + 16 * kt + 4 * h);
        f32x4 b = *(const f32x4*)(xr + 16 * kt + 8 + 4 * h);
        *(f32x4*)(zr + 16 * kt + 4 * h) = a;
        *(f32x4*)(zr + 16 * kt + 8 + 4 * h) = b;
        x0f[kt] = pack4(pkrtz(a[0], a[1]), pkrtz(a[2], a[3]), pkrtz(b[0], b[1]), pkrtz(b[2], b[3]));
    }

    // x1 resident as packed f16 (16 regs). x1h[t*2+q][e] <-> feature 32t+16q+8*(e>=4)+4h+(e&3)
    f16x8 x1h[4];
#pragma unroll
    for (int i = 0; i < 4; ++i) {
        const int t = i >> 1, q = i & 1;
        f32x4 a = *(const f32x4*)(xr + 64 + 32 * t + 16 * q + 4 * h);
        f32x4 b = *(const f32x4*)(xr + 64 + 32 * t + 16 * q + 8 + 4 * h);
        x1h[i] = pack4(pkrtz(a[0], a[1]), pkrtz(a[2], a[3]),
                       pkrtz(b[0], b[1]), pkrtz(b[2], b[3]));
    }

    __syncthreads();   // implicit vmcnt(0) drain: s0 DMA complete

    // logdet via Σs = count - 2·Σrc  (rc = 1/(e^{2y}+1); s = tanh(y) = 1-2rc)
    float sumrc = 0.f;
#pragma unroll 1
    for (int l = 0; l < 5; ++l) {
        // ---- s phase: compute from slot0; DMA t_l -> slot1 flies under it ----
        stage(2 * l + 1, wl + SLOTB);

        f32x16 cs[2];
        mlp3(wl, x0f, lane, cs);

        // x1 *= exp(s), packed f16; accumulate Σrc for logdet
#pragma unroll
        for (int i = 0; i < 4; ++i) {
            const int t = i >> 1, q = i & 1;
            float ef[8];
#pragma unroll
            for (int e = 0; e < 8; ++e) {
                float y = cs[t][8 * q + e];
                float u = __builtin_amdgcn_exp2f(2.8853900817779268f * y);  // e^{2y}
                float rc = __builtin_amdgcn_rcpf(u + 1.f);
                sumrc += rc;
                // exp(tanh(y)) = exp2(log2e - 2*log2e*rc)
                ef[e] = __builtin_amdgcn_exp2f(fmaf(-2.8853900817779268f, rc, 1.4426950408889634f));
            }
            f16x8 efp = pack4(pkrtz(ef[0], ef[1]), pkrtz(ef[2], ef[3]),
                              pkrtz(ef[4], ef[5]), pkrtz(ef[6], ef[7]));
            x1h[i] = x1h[i] * efp;   // v_pk_mul_f16
        }

        __syncthreads();   // slot0 reads done; slot1 DMA drained

        // ---- t phase: compute from slot1; DMA s_{l+1} -> slot0 flies under it ----
        if (l < 4) stage(2 * l + 2, wl);

        f32x16 ct[2];
        mlp3(wl + SLOTB, x0f, lane, ct);

        // x1 += t, packed f16
#pragma unroll
        for (int i = 0; i < 4; ++i) {
            const int t = i >> 1, q = i & 1;
            f16x8 tp = pack4(pkrtz(ct[t][8 * q + 0], ct[t][8 * q + 1]),
                             pkrtz(ct[t][8 * q + 2], ct[t][8 * q + 3]),
                             pkrtz(ct[t][8 * q + 4], ct[t][8 * q + 5]),
                             pkrtz(ct[t][8 * q + 6], ct[t][8 * q + 7]));
            x1h[i] = x1h[i] + tp;   // v_pk_add_f16
        }

        __syncthreads();   // slot1 reads done; slot0 DMA drained
    }

    // Store z[:, 64:]
#pragma unroll
    for (int i = 0; i < 4; ++i) {
        const int t = i >> 1, q = i & 1;
        f16x8 v = x1h[i];
        f32x4 a = {(float)v[0], (float)v[1], (float)v[2], (float)v[3]};
        f32x4 b = {(float)v[4], (float)v[5], (float)v[6], (float)v[7]};
        *(f32x4*)(zr + 64 + 32 * t + 16 * q + 4 * h) = a;
        *(f32x4*)(zr + 64 + 32 * t + 16 * q + 8 + 4 * h) = b;
    }

    // log_det = 320 - 2·Σrc (both lane halves); lane n and n+32 split the features.
    float sr2 = sumrc + __shfl_xor(sumrc, 32);
    if (h == 0) out[(size_t)nrows * 128 + n] = fmaf(-2.f, sr2, 320.f);
}

extern "C" void kernel_launch(void* const* d_in, const int* in_sizes, int n_in,
                              void* d_out, int out_size, void* d_ws, size_t ws_size,
                              hipStream_t stream) {
    const float* x   = (const float*)d_in[0];
    const float* sW1 = (const float*)d_in[1];
    const float* sb1 = (const float*)d_in[2];
    const float* sW2 = (const float*)d_in[3];
    const float* sb2 = (const float*)d_in[4];
    const float* sW3 = (const float*)d_in[5];
    const float* sb3 = (const float*)d_in[6];
    const float* tW1 = (const float*)d_in[7];
    const float* tb1 = (const float*)d_in[8];
    const float* tW2 = (const float*)d_in[9];
    const float* tb2 = (const float*)d_in[10];
    const float* tW3 = (const float*)d_in[11];
    const float* tb3 = (const float*)d_in[12];

    f16* wp = (f16*)d_ws;      // weights: 240 KB frag-packed (path-major); biases at +480 KB
    char* wb = (char*)d_ws + 491520;
    int nrows = in_sizes[0] / 128;

    pack_w<<<30, 512, 0, stream>>>(sW1, sW2, sW3, tW1, tW2, tW3, wp);
    pack_b<<<4, 512, 0, stream>>>(sb1, sb2, sb3, tb1, tb2, tb3, wb);
    flow_main<<<nrows / 256, 512, 0, stream>>>(x, wp, (float*)d_out, nrows);
}